// Round 4
// baseline (197.171 us; speedup 1.0000x reference)
//
#include <hip/hip_runtime.h>

typedef unsigned short u16;
typedef __attribute__((ext_vector_type(8))) short bf16x8;
typedef __attribute__((ext_vector_type(4))) float f32x4;
typedef __attribute__((ext_vector_type(4))) unsigned short u16x4;

#define MFMA16 __builtin_amdgcn_mfma_f32_16x16x32_bf16

__device__ inline u16 f2bf(float f) {            // cheap round-half-up
    union { float f; unsigned u; } v; v.f = f;
    return (u16)((v.u + 0x8000u) >> 16);
}

// pack two f32 -> one u32 of 2x bf16 (RNE), T12 recipe (no builtin on gfx950)
__device__ inline unsigned cvtpk(float lo, float hi) {
    unsigned r;
    asm("v_cvt_pk_bf16_f32 %0, %1, %2" : "=v"(r) : "v"(lo), "v"(hi));
    return r;
}

// async global->LDS, 16 B/lane. LDS dest = wave-uniform base + lane*16.
__device__ inline void gld16(const u16* g, u16* l) {
    __builtin_amdgcn_global_load_lds(
        (const __attribute__((address_space(1))) unsigned int*)g,
        (__attribute__((address_space(3))) unsigned int*)l, 16, 0, 0);
}

// ---------------- fp32 -> bf16 conversion ----------------
// Exact 1D grid: tensors 0-2 are 4M elems (2048 blocks each), 3-6 are 1M (512 each).
struct CvtArgs { const float* src[7]; u16* dst[7]; };

__global__ __launch_bounds__(256) void cvt_kernel(CvtArgs a) {
    const int bid = blockIdx.x;
    int z, local;
    if (bid < 6144) { z = bid >> 11; local = bid & 2047; }
    else            { z = 3 + ((bid - 6144) >> 9); local = (bid - 6144) & 511; }
    const size_t i = ((size_t)local * 256 + threadIdx.x) * 8;
    const float* s = a.src[z];
    float4 v0 = *(const float4*)(s + i);
    float4 v1 = *(const float4*)(s + i + 4);
    union { u16 h[8]; bf16x8 v; } o;
    o.h[0] = f2bf(v0.x); o.h[1] = f2bf(v0.y); o.h[2] = f2bf(v0.z); o.h[3] = f2bf(v0.w);
    o.h[4] = f2bf(v1.x); o.h[5] = f2bf(v1.y); o.h[6] = f2bf(v1.z); o.h[7] = f2bf(v1.w);
    *(bf16x8*)(a.dst[z] + i) = o.v;
}

// ---------------- QKV GEMM: 128x128 tile, BK=64, XCD-swizzled ----------------
struct GemmArgs { const u16* A; const u16* W; const float* bias; void* out; int epi; };
struct Gemm3Args { GemmArgs g[3]; };

__global__ __launch_bounds__(256, 3) void gemm_qkv(Gemm3Args ga) {
    __shared__ u16 lA[128 * 64];
    __shared__ u16 lB[128 * 64];
    const GemmArgs g = ga.g[blockIdx.z];
    const int t = threadIdx.x, wave = t >> 6, lane = t & 63;
    const int quad = lane >> 4, l16 = lane & 15;
    // XCD swizzle: xcd = bid&7 owns mtiles [xcd*4, xcd*4+4) x all 8 ntiles
    const int bid = blockIdx.x;
    const int mtile = (bid & 7) * 4 + (bid >> 6);
    const int ntile = (bid >> 3) & 7;
    const int rowsA = mtile * 128, rowsB = ntile * 128;
    const int wm = (wave >> 1) * 64, wn = (wave & 1) * 64;
    const u16* A = g.A; const u16* W = g.W;

    f32x4 acc[4][4] = {};

    for (int kb = 0; kb < 1024; kb += 64) {
#pragma unroll
        for (int i = 0; i < 4; i++) {
            int u = (i * 4 + wave) * 64 + lane;
            int row = u >> 3, cu = (u & 7) ^ (row & 7);
            gld16(A + (size_t)(rowsA + row) * 1024 + kb + cu * 8, lA + u * 8);
        }
#pragma unroll
        for (int i = 0; i < 4; i++) {
            int u = (i * 4 + wave) * 64 + lane;
            int row = u >> 3, cu = (u & 7) ^ (row & 7);
            gld16(W + (size_t)(rowsB + row) * 1024 + kb + cu * 8, lB + u * 8);
        }
        __syncthreads();

        bf16x8 af[4][2], bfr[4][2];
#pragma unroll
        for (int mi = 0; mi < 4; mi++) {
            int row = wm + mi * 16 + l16;
#pragma unroll
            for (int kr = 0; kr < 2; kr++)
                af[mi][kr] = *(const bf16x8*)(lA + row * 64 + (((kr * 4 + quad) ^ (row & 7)) * 8));
        }
#pragma unroll
        for (int ni = 0; ni < 4; ni++) {
            int row = wn + ni * 16 + l16;
#pragma unroll
            for (int kr = 0; kr < 2; kr++)
                bfr[ni][kr] = *(const bf16x8*)(lB + row * 64 + (((kr * 4 + quad) ^ (row & 7)) * 8));
        }
#pragma unroll
        for (int mi = 0; mi < 4; mi++)
#pragma unroll
            for (int ni = 0; ni < 4; ni++) {
                acc[mi][ni] = MFMA16(af[mi][0], bfr[ni][0], acc[mi][ni], 0, 0, 0);
                acc[mi][ni] = MFMA16(af[mi][1], bfr[ni][1], acc[mi][ni], 0, 0, 0);
            }
        __syncthreads();
    }

    const int epi = g.epi;
#pragma unroll
    for (int ni = 0; ni < 4; ni++) {
        const int ncol = rowsB + wn + ni * 16 + l16;
        const float bv = g.bias[ncol];
        const int h = ncol >> 6, hd = ncol & 63;
#pragma unroll
        for (int mi = 0; mi < 4; mi++) {
            const int mrow0 = rowsA + wm + mi * 16 + quad * 4;
            const int b = mrow0 >> 10, l0 = mrow0 & 1023;
            if (epi == 0) {
#pragma unroll
                for (int r = 0; r < 4; r++)
                    ((u16*)g.out)[((size_t)(b * 16 + h) * 1024 + l0 + r) * 64 + hd] =
                        f2bf(acc[mi][ni][r] + bv);
            } else {
                u16x4 pk;
#pragma unroll
                for (int r = 0; r < 4; r++) pk[r] = f2bf(acc[mi][ni][r] + bv);
                *(u16x4*)((u16*)g.out + ((size_t)(b * 16 + h) * 64 + hd) * 1024 + l0) = pk;
            }
        }
    }
}

// ---------------- P GEMM: 128x64 tile, BK=64, fp32 out, XCD-swizzled ----------------
__global__ __launch_bounds__(256, 2) void gemm_p(const u16* __restrict__ A,
                                                 const u16* __restrict__ W,
                                                 const float* __restrict__ bias,
                                                 float* __restrict__ out)
{
    __shared__ u16 lA[128 * 64];
    __shared__ u16 lB[64 * 64];
    const int t = threadIdx.x, wave = t >> 6, lane = t & 63;
    const int quad = lane >> 4, l16 = lane & 15;
    // XCD swizzle: xcd = bid&7 owns mtiles [xcd*4, xcd*4+4) x all 16 ntiles
    const int bid = blockIdx.x;
    const int mtile = (bid & 7) * 4 + (bid >> 7);
    const int ntile = (bid >> 3) & 15;
    const int rowsA = mtile * 128, rowsB = ntile * 64;
    const int wm = (wave >> 1) * 64, wn = (wave & 1) * 32;

    f32x4 acc[4][2] = {};

    for (int kb = 0; kb < 1024; kb += 64) {
#pragma unroll
        for (int i = 0; i < 4; i++) {
            int u = (i * 4 + wave) * 64 + lane;
            int row = u >> 3, cu = (u & 7) ^ (row & 7);
            gld16(A + (size_t)(rowsA + row) * 1024 + kb + cu * 8, lA + u * 8);
        }
#pragma unroll
        for (int i = 0; i < 2; i++) {
            int u = (i * 4 + wave) * 64 + lane;
            int row = u >> 3, cu = (u & 7) ^ (row & 7);
            gld16(W + (size_t)(rowsB + row) * 1024 + kb + cu * 8, lB + u * 8);
        }
        __syncthreads();

        bf16x8 af[4][2], bfr[2][2];
#pragma unroll
        for (int mi = 0; mi < 4; mi++) {
            int row = wm + mi * 16 + l16;
#pragma unroll
            for (int kr = 0; kr < 2; kr++)
                af[mi][kr] = *(const bf16x8*)(lA + row * 64 + (((kr * 4 + quad) ^ (row & 7)) * 8));
        }
#pragma unroll
        for (int ni = 0; ni < 2; ni++) {
            int row = wn + ni * 16 + l16;
#pragma unroll
            for (int kr = 0; kr < 2; kr++)
                bfr[ni][kr] = *(const bf16x8*)(lB + row * 64 + (((kr * 4 + quad) ^ (row & 7)) * 8));
        }
#pragma unroll
        for (int mi = 0; mi < 4; mi++)
#pragma unroll
            for (int ni = 0; ni < 2; ni++) {
                acc[mi][ni] = MFMA16(af[mi][0], bfr[ni][0], acc[mi][ni], 0, 0, 0);
                acc[mi][ni] = MFMA16(af[mi][1], bfr[ni][1], acc[mi][ni], 0, 0, 0);
            }
        __syncthreads();
    }

#pragma unroll
    for (int ni = 0; ni < 2; ni++) {
        const int ncol = rowsB + wn + ni * 16 + l16;
        const float bv = bias[ncol];
#pragma unroll
        for (int mi = 0; mi < 4; mi++) {
            const int mrow0 = rowsA + wm + mi * 16 + quad * 4;
#pragma unroll
            for (int r = 0; r < 4; r++)
                out[(size_t)(mrow0 + r) * 1024 + ncol] = acc[mi][ni][r] + bv;
        }
    }
}

// ---------------- flash attention: paired causal-complement q-blocks ----------------
// grid = 512 uniform blocks (2/CU). Block handles q-blocks qbA=pr, qbB=15-pr of one
// head: exactly 17 tile-computes, staged over the union of k-tiles (16-pr stagings).
// 2-phase double-buffered staging; one barrier per pass.
// SWAPPED QK^T (T12): sc = mfma(K, Q) puts P[q=l16][k] lane-local -> softmax fully
// in-register, P->bf16 via v_cvt_pk_bf16_f32 (8/block-step), NO LDS P round-trip.
// V fragments read as paired ds_read_b64 with the matching per-lane k-sequence
// (k = kr*32 + (jj>>2)*16 + quad*4 + (jj&3)); MFMA only needs A/B k-order to agree.
// lacc via mfma(P, ones): D[q][*] lands row-sum exactly in the epilogue layout.
__global__ __launch_bounds__(256, 2) void attn_kernel(const u16* __restrict__ qh,
                                                      const u16* __restrict__ kh,
                                                      const u16* __restrict__ vhT,
                                                      u16* __restrict__ y)
{
    __shared__ u16 sK[2][64 * 64];
    __shared__ u16 sVT[2][64 * 64];

    const int t = threadIdx.x, wave = t >> 6, lane = t & 63;
    const int quad = lane >> 4, l16 = lane & 15;
    const int bid = blockIdx.x;
    const int bh = (bid & 7) * 8 + ((bid >> 3) & 7);
    const int pr = bid >> 6;                           // 0..7
    const int qbaseA = pr * 64 + wave * 16;            // short q-block
    const int qbaseB = (15 - pr) * 64 + wave * 16;     // long q-block
    const size_t base = (size_t)bh * 1024 * 64;
    const float e2 = 0.18033688f;                      // 0.125 * log2(e)

    bf16x8 aqA[2], aqB[2];
#pragma unroll
    for (int kr = 0; kr < 2; kr++) {
        aqA[kr] = *(const bf16x8*)(qh + base + (size_t)(qbaseA + l16) * 64 + kr * 32 + quad * 8);
        aqB[kr] = *(const bf16x8*)(qh + base + (size_t)(qbaseB + l16) * 64 + kr * 32 + quad * 8);
    }

    bf16x8 ones;
#pragma unroll
    for (int j = 0; j < 8; j++) ones[j] = (short)0x3F80;

    f32x4 oA[4] = {}, oB[4] = {};
    f32x4 laccA = {}, laccB = {};

    auto STAGE = [&](int kb, int b) {
        const int krow0 = kb * 64;
#pragma unroll
        for (int i = 0; i < 2; i++) {
            int u = (i * 4 + wave) * 64 + lane;
            int row = u >> 3, cu = (u & 7) ^ (row & 7);
            gld16(kh + base + (size_t)(krow0 + row) * 64 + cu * 8, &sK[b][0] + u * 8);
        }
#pragma unroll
        for (int i = 0; i < 2; i++) {
            int u = (i * 4 + wave) * 64 + lane;
            int row = u >> 3, cu = (u & 7) ^ (row & 7);
            gld16(vhT + ((size_t)(bh * 64 + row)) * 1024 + krow0 + cu * 8, &sVT[b][0] + u * 8);
        }
    };

    STAGE(0, 0);
    __syncthreads();

    const int last = 15 - pr;
    int cur = 0;
    for (int kb = 0; kb <= last; kb++) {
        if (kb < last) STAGE(kb + 1, cur ^ 1);         // prefetch overlaps compute
        const int krow0 = kb * 64;
        const bool actA = (kb <= pr);
        const u16* sKc = sK[cur];
        const u16* sVc = sVT[cur];

        bf16x8 bk[4][2];
#pragma unroll
        for (int kc = 0; kc < 4; kc++) {
            int row = kc * 16 + l16;
#pragma unroll
            for (int kr = 0; kr < 2; kr++)
                bk[kc][kr] = *(const bf16x8*)(sKc + row * 64 + (((kr * 4 + quad) ^ (row & 7)) * 8));
        }
        // swapped QK^T: sc[kc][r] = S[q = qbase+l16][k = krow0 + kc*16 + quad*4 + r]
        f32x4 scA[4], scB[4];
        __builtin_amdgcn_s_setprio(1);
#pragma unroll
        for (int kc = 0; kc < 4; kc++) {
            f32x4 z = {};
            z = MFMA16(bk[kc][0], aqB[0], z, 0, 0, 0);
            z = MFMA16(bk[kc][1], aqB[1], z, 0, 0, 0);
            scB[kc] = z;
        }
        if (actA) {
#pragma unroll
            for (int kc = 0; kc < 4; kc++) {
                f32x4 z = {};
                z = MFMA16(bk[kc][0], aqA[0], z, 0, 0, 0);
                z = MFMA16(bk[kc][1], aqA[1], z, 0, 0, 0);
                scA[kc] = z;
            }
        }
        __builtin_amdgcn_s_setprio(0);

        // ---- in-register softmax + pack (no LDS) ----
        bf16x8 apA[2], apB[2];
        if (actA) {
            const bool dmA = (krow0 + 63 > qbaseA);
            const int qrowA = qbaseA + l16;
#pragma unroll
            for (int kc = 0; kc < 4; kc++)
#pragma unroll
                for (int r = 0; r < 4; r++) {
                    float xv = fminf(scA[kc][r] * e2, 43.f);
                    float pv = exp2f(xv);
                    if (dmA) {
                        int kcol = krow0 + kc * 16 + quad * 4 + r;
                        if (kcol > qrowA) pv = 0.f;
                    }
                    scA[kc][r] = pv;
                }
#pragma unroll
            for (int kr = 0; kr < 2; kr++) {
                union { unsigned w[4]; bf16x8 v; } u;
#pragma unroll
                for (int w = 0; w < 4; w++) {
                    int kc = kr * 2 + (w >> 1);
                    int r0 = (w & 1) * 2;
                    u.w[w] = cvtpk(scA[kc][r0], scA[kc][r0 + 1]);
                }
                apA[kr] = u.v;
            }
        }
        {
            const bool dmB = (krow0 + 63 > qbaseB);
            const int qrowB = qbaseB + l16;
#pragma unroll
            for (int kc = 0; kc < 4; kc++)
#pragma unroll
                for (int r = 0; r < 4; r++) {
                    float xv = fminf(scB[kc][r] * e2, 43.f);
                    float pv = exp2f(xv);
                    if (dmB) {
                        int kcol = krow0 + kc * 16 + quad * 4 + r;
                        if (kcol > qrowB) pv = 0.f;
                    }
                    scB[kc][r] = pv;
                }
#pragma unroll
            for (int kr = 0; kr < 2; kr++) {
                union { unsigned w[4]; bf16x8 v; } u;
#pragma unroll
                for (int w = 0; w < 4; w++) {
                    int kc = kr * 2 + (w >> 1);
                    int r0 = (w & 1) * 2;
                    u.w[w] = cvtpk(scB[kc][r0], scB[kc][r0 + 1]);
                }
                apB[kr] = u.v;
            }
        }

        // V fragments: per-lane k-seq = kr*32 + (jj>>2)*16 + quad*4 + (jj&3)
        bf16x8 bv[4][2];
#pragma unroll
        for (int nt = 0; nt < 4; nt++) {
            int row = nt * 16 + l16;
            const u16* rp = sVc + row * 64;
#pragma unroll
            for (int kr = 0; kr < 2; kr++) {
                int g0 = kr * 4 + (quad >> 1);
                int off = (quad & 1) * 4;
                union { u16x4 q[2]; bf16x8 v; } u;
                u.q[0] = *(const u16x4*)(rp + ((g0 ^ (row & 7)) * 8 + off));
                u.q[1] = *(const u16x4*)(rp + (((g0 + 2) ^ (row & 7)) * 8 + off));
                bv[nt][kr] = u.v;
            }
        }

        __builtin_amdgcn_s_setprio(1);
#pragma unroll
        for (int nt = 0; nt < 4; nt++) {
            oB[nt] = MFMA16(apB[0], bv[nt][0], oB[nt], 0, 0, 0);
            oB[nt] = MFMA16(apB[1], bv[nt][1], oB[nt], 0, 0, 0);
        }
        laccB = MFMA16(apB[0], ones, laccB, 0, 0, 0);
        laccB = MFMA16(apB[1], ones, laccB, 0, 0, 0);
        if (actA) {
#pragma unroll
            for (int nt = 0; nt < 4; nt++) {
                oA[nt] = MFMA16(apA[0], bv[nt][0], oA[nt], 0, 0, 0);
                oA[nt] = MFMA16(apA[1], bv[nt][1], oA[nt], 0, 0, 0);
            }
            laccA = MFMA16(apA[0], ones, laccA, 0, 0, 0);
            laccA = MFMA16(apA[1], ones, laccA, 0, 0, 0);
        }
        __builtin_amdgcn_s_setprio(0);
        __syncthreads();
        cur ^= 1;
    }

    const int b = bh >> 4, h = bh & 15;
#pragma unroll
    for (int nt = 0; nt < 4; nt++)
#pragma unroll
        for (int r = 0; r < 4; r++) {
            int d = nt * 16 + l16;
            int qrA = qbaseA + quad * 4 + r;
            int qrB = qbaseB + quad * 4 + r;
            y[(size_t)(b * 1024 + qrA) * 1024 + h * 64 + d] = f2bf(oA[nt][r] / laccA[r]);
            y[(size_t)(b * 1024 + qrB) * 1024 + h * 64 + d] = f2bf(oB[nt][r] / laccB[r]);
        }
}

extern "C" void kernel_launch(void* const* d_in, const int* in_sizes, int n_in,
                              void* d_out, int out_size, void* d_ws, size_t ws_size,
                              hipStream_t stream)
{
    const float* key   = (const float*)d_in[0];
    const float* value = (const float*)d_in[1];
    const float* query = (const float*)d_in[2];
    const float* Wk = (const float*)d_in[3];
    const float* bk = (const float*)d_in[4];
    const float* Wq = (const float*)d_in[5];
    const float* bq = (const float*)d_in[6];
    const float* Wv = (const float*)d_in[7];
    const float* bv = (const float*)d_in[8];
    const float* Wp = (const float*)d_in[9];
    const float* bp = (const float*)d_in[10];

    char* ws = (char*)d_ws;
    u16* xq  = (u16*)(ws + (size_t)( 0 << 20));
    u16* xk  = (u16*)(ws + (size_t)( 8 << 20));
    u16* xv  = (u16*)(ws + (size_t)(16 << 20));
    u16* wqb = (u16*)(ws + (size_t)(24 << 20));
    u16* wkb = (u16*)(ws + (size_t)(26 << 20));
    u16* wvb = (u16*)(ws + (size_t)(28 << 20));
    u16* wpb = (u16*)(ws + (size_t)(30 << 20));
    u16* qh  = (u16*)(ws + (size_t)(32 << 20));
    u16* kh  = (u16*)(ws + (size_t)(40 << 20));
    u16* vhT = (u16*)(ws + (size_t)(48 << 20));
    u16* y   = xq;   // xq dead after QKV GEMM

    CvtArgs ca;
    ca.src[0] = query; ca.dst[0] = xq;
    ca.src[1] = key;   ca.dst[1] = xk;
    ca.src[2] = value; ca.dst[2] = xv;
    ca.src[3] = Wq;    ca.dst[3] = wqb;
    ca.src[4] = Wk;    ca.dst[4] = wkb;
    ca.src[5] = Wv;    ca.dst[5] = wvb;
    ca.src[6] = Wp;    ca.dst[6] = wpb;
    hipLaunchKernelGGL(cvt_kernel, dim3(8192), dim3(256), 0, stream, ca);

    Gemm3Args g3;
    g3.g[0] = GemmArgs{xq, wqb, bq, (void*)qh,  0};
    g3.g[1] = GemmArgs{xk, wkb, bk, (void*)kh,  0};
    g3.g[2] = GemmArgs{xv, wvb, bv, (void*)vhT, 2};
    hipLaunchKernelGGL(gemm_qkv, dim3(256, 1, 3), dim3(256), 0, stream, g3);

    hipLaunchKernelGGL(attn_kernel, dim3(512), dim3(256), 0, stream, qh, kh, vhT, y);

    hipLaunchKernelGGL(gemm_p, dim3(512), dim3(256), 0, stream, y, wpb, bp, (float*)d_out);
}

// Round 5
// 191.364 us; speedup vs baseline: 1.0303x; 1.0303x over previous
//
#include <hip/hip_runtime.h>

typedef unsigned short u16;
typedef __attribute__((ext_vector_type(8))) short bf16x8;
typedef __attribute__((ext_vector_type(4))) float f32x4;
typedef __attribute__((ext_vector_type(4))) unsigned short u16x4;

#define MFMA16 __builtin_amdgcn_mfma_f32_16x16x32_bf16

__device__ inline u16 f2bf(float f) {            // cheap round-half-up
    union { float f; unsigned u; } v; v.f = f;
    return (u16)((v.u + 0x8000u) >> 16);
}

// async global->LDS, 16 B/lane. LDS dest = wave-uniform base + lane*16.
__device__ inline void gld16(const u16* g, u16* l) {
    __builtin_amdgcn_global_load_lds(
        (const __attribute__((address_space(1))) unsigned int*)g,
        (__attribute__((address_space(3))) unsigned int*)l, 16, 0, 0);
}

// ---------------- fp32 -> bf16 conversion ----------------
// Exact 1D grid: tensors 0-2 are 4M elems (2048 blocks each), 3-6 are 1M (512 each).
struct CvtArgs { const float* src[7]; u16* dst[7]; };

__global__ __launch_bounds__(256) void cvt_kernel(CvtArgs a) {
    const int bid = blockIdx.x;
    int z, local;
    if (bid < 6144) { z = bid >> 11; local = bid & 2047; }
    else            { z = 3 + ((bid - 6144) >> 9); local = (bid - 6144) & 511; }
    const size_t i = ((size_t)local * 256 + threadIdx.x) * 8;
    const float* s = a.src[z];
    float4 v0 = *(const float4*)(s + i);
    float4 v1 = *(const float4*)(s + i + 4);
    union { u16 h[8]; bf16x8 v; } o;
    o.h[0] = f2bf(v0.x); o.h[1] = f2bf(v0.y); o.h[2] = f2bf(v0.z); o.h[3] = f2bf(v0.w);
    o.h[4] = f2bf(v1.x); o.h[5] = f2bf(v1.y); o.h[6] = f2bf(v1.z); o.h[7] = f2bf(v1.w);
    *(bf16x8*)(a.dst[z] + i) = o.v;
}

// ---------------- QKV GEMM: 128x128 tile, BK=64, XCD-swizzled ----------------
struct GemmArgs { const u16* A; const u16* W; const float* bias; void* out; int epi; };
struct Gemm3Args { GemmArgs g[3]; };

__global__ __launch_bounds__(256, 3) void gemm_qkv(Gemm3Args ga) {
    __shared__ u16 lA[128 * 64];
    __shared__ u16 lB[128 * 64];
    const GemmArgs g = ga.g[blockIdx.z];
    const int t = threadIdx.x, wave = t >> 6, lane = t & 63;
    const int quad = lane >> 4, l16 = lane & 15;
    // XCD swizzle: xcd = bid&7 owns mtiles [xcd*4, xcd*4+4) x all 8 ntiles
    const int bid = blockIdx.x;
    const int mtile = (bid & 7) * 4 + (bid >> 6);
    const int ntile = (bid >> 3) & 7;
    const int rowsA = mtile * 128, rowsB = ntile * 128;
    const int wm = (wave >> 1) * 64, wn = (wave & 1) * 64;
    const u16* A = g.A; const u16* W = g.W;

    f32x4 acc[4][4] = {};

    for (int kb = 0; kb < 1024; kb += 64) {
#pragma unroll
        for (int i = 0; i < 4; i++) {
            int u = (i * 4 + wave) * 64 + lane;
            int row = u >> 3, cu = (u & 7) ^ (row & 7);
            gld16(A + (size_t)(rowsA + row) * 1024 + kb + cu * 8, lA + u * 8);
        }
#pragma unroll
        for (int i = 0; i < 4; i++) {
            int u = (i * 4 + wave) * 64 + lane;
            int row = u >> 3, cu = (u & 7) ^ (row & 7);
            gld16(W + (size_t)(rowsB + row) * 1024 + kb + cu * 8, lB + u * 8);
        }
        __syncthreads();

        bf16x8 af[4][2], bfr[4][2];
#pragma unroll
        for (int mi = 0; mi < 4; mi++) {
            int row = wm + mi * 16 + l16;
#pragma unroll
            for (int kr = 0; kr < 2; kr++)
                af[mi][kr] = *(const bf16x8*)(lA + row * 64 + (((kr * 4 + quad) ^ (row & 7)) * 8));
        }
#pragma unroll
        for (int ni = 0; ni < 4; ni++) {
            int row = wn + ni * 16 + l16;
#pragma unroll
            for (int kr = 0; kr < 2; kr++)
                bfr[ni][kr] = *(const bf16x8*)(lB + row * 64 + (((kr * 4 + quad) ^ (row & 7)) * 8));
        }
#pragma unroll
        for (int mi = 0; mi < 4; mi++)
#pragma unroll
            for (int ni = 0; ni < 4; ni++) {
                acc[mi][ni] = MFMA16(af[mi][0], bfr[ni][0], acc[mi][ni], 0, 0, 0);
                acc[mi][ni] = MFMA16(af[mi][1], bfr[ni][1], acc[mi][ni], 0, 0, 0);
            }
        __syncthreads();
    }

    const int epi = g.epi;
#pragma unroll
    for (int ni = 0; ni < 4; ni++) {
        const int ncol = rowsB + wn + ni * 16 + l16;
        const float bv = g.bias[ncol];
        const int h = ncol >> 6, hd = ncol & 63;
#pragma unroll
        for (int mi = 0; mi < 4; mi++) {
            const int mrow0 = rowsA + wm + mi * 16 + quad * 4;
            const int b = mrow0 >> 10, l0 = mrow0 & 1023;
            if (epi == 0) {
#pragma unroll
                for (int r = 0; r < 4; r++)
                    ((u16*)g.out)[((size_t)(b * 16 + h) * 1024 + l0 + r) * 64 + hd] =
                        f2bf(acc[mi][ni][r] + bv);
            } else {
                u16x4 pk;
#pragma unroll
                for (int r = 0; r < 4; r++) pk[r] = f2bf(acc[mi][ni][r] + bv);
                *(u16x4*)((u16*)g.out + ((size_t)(b * 16 + h) * 64 + hd) * 1024 + l0) = pk;
            }
        }
    }
}

// ---------------- P GEMM: 128x128 tile (same structure as qkv), fp32 out ----------
// Upgraded from 128x64: doubles MFMA-per-barrier density (32 vs 16 MFMA/wave/K-step)
// -> same staging/barrier cost amortized over 2x compute. Grid 256, XCD-swizzled.
__global__ __launch_bounds__(256, 3) void gemm_p(const u16* __restrict__ A,
                                                 const u16* __restrict__ W,
                                                 const float* __restrict__ bias,
                                                 float* __restrict__ out)
{
    __shared__ u16 lA[128 * 64];
    __shared__ u16 lB[128 * 64];
    const int t = threadIdx.x, wave = t >> 6, lane = t & 63;
    const int quad = lane >> 4, l16 = lane & 15;
    const int bid = blockIdx.x;
    const int mtile = (bid & 7) * 4 + (bid >> 6);
    const int ntile = (bid >> 3) & 7;
    const int rowsA = mtile * 128, rowsB = ntile * 128;
    const int wm = (wave >> 1) * 64, wn = (wave & 1) * 64;

    f32x4 acc[4][4] = {};

    for (int kb = 0; kb < 1024; kb += 64) {
#pragma unroll
        for (int i = 0; i < 4; i++) {
            int u = (i * 4 + wave) * 64 + lane;
            int row = u >> 3, cu = (u & 7) ^ (row & 7);
            gld16(A + (size_t)(rowsA + row) * 1024 + kb + cu * 8, lA + u * 8);
        }
#pragma unroll
        for (int i = 0; i < 4; i++) {
            int u = (i * 4 + wave) * 64 + lane;
            int row = u >> 3, cu = (u & 7) ^ (row & 7);
            gld16(W + (size_t)(rowsB + row) * 1024 + kb + cu * 8, lB + u * 8);
        }
        __syncthreads();

        bf16x8 af[4][2], bfr[4][2];
#pragma unroll
        for (int mi = 0; mi < 4; mi++) {
            int row = wm + mi * 16 + l16;
#pragma unroll
            for (int kr = 0; kr < 2; kr++)
                af[mi][kr] = *(const bf16x8*)(lA + row * 64 + (((kr * 4 + quad) ^ (row & 7)) * 8));
        }
#pragma unroll
        for (int ni = 0; ni < 4; ni++) {
            int row = wn + ni * 16 + l16;
#pragma unroll
            for (int kr = 0; kr < 2; kr++)
                bfr[ni][kr] = *(const bf16x8*)(lB + row * 64 + (((kr * 4 + quad) ^ (row & 7)) * 8));
        }
#pragma unroll
        for (int mi = 0; mi < 4; mi++)
#pragma unroll
            for (int ni = 0; ni < 4; ni++) {
                acc[mi][ni] = MFMA16(af[mi][0], bfr[ni][0], acc[mi][ni], 0, 0, 0);
                acc[mi][ni] = MFMA16(af[mi][1], bfr[ni][1], acc[mi][ni], 0, 0, 0);
            }
        __syncthreads();
    }

#pragma unroll
    for (int ni = 0; ni < 4; ni++) {
        const int ncol = rowsB + wn + ni * 16 + l16;
        const float bv = bias[ncol];
#pragma unroll
        for (int mi = 0; mi < 4; mi++) {
            const int mrow0 = rowsA + wm + mi * 16 + quad * 4;
#pragma unroll
            for (int r = 0; r < 4; r++)
                out[(size_t)(mrow0 + r) * 1024 + ncol] = acc[mi][ni][r] + bv;
        }
    }
}

// ---------------- flash attention: paired causal-complement q-blocks ----------------
// grid = 512 uniform blocks (2/CU steady). Block handles q-blocks qbA=pr and
// qbB=15-pr of one head: exactly 17 tile-computes per block (uniform),
// staged over the UNION of needed k-tiles (16-pr stagings; both q-blocks
// consume the same staged K/V tile). 2-phase double-buffered staging:
// issue next tile's global_load_lds before computing current; one barrier/pass.
// bh = (bid&7)*8 + ((bid>>3)&7): co-resident blocks share a head's K/V stream.
// (R4's swapped-QK^T/cvt_pk variant measured no better -> reverted to this.)
__global__ __launch_bounds__(256, 2) void attn_kernel(const u16* __restrict__ qh,
                                                      const u16* __restrict__ kh,
                                                      const u16* __restrict__ vhT,
                                                      u16* __restrict__ y)
{
    __shared__ u16 sK[2][64 * 64];
    __shared__ u16 sVT[2][64 * 64];
    __shared__ u16 sP[4 * 16 * 72];

    const int t = threadIdx.x, wave = t >> 6, lane = t & 63;
    const int quad = lane >> 4, l16 = lane & 15;
    const int bid = blockIdx.x;
    const int bh = (bid & 7) * 8 + ((bid >> 3) & 7);
    const int pr = bid >> 6;                           // 0..7
    const int qbaseA = pr * 64 + wave * 16;            // short q-block
    const int qbaseB = (15 - pr) * 64 + wave * 16;     // long q-block
    const size_t base = (size_t)bh * 1024 * 64;
    const float e2 = 0.18033688f;                      // 0.125 * log2(e)

    bf16x8 aqA[2], aqB[2];
#pragma unroll
    for (int kr = 0; kr < 2; kr++) {
        aqA[kr] = *(const bf16x8*)(qh + base + (size_t)(qbaseA + l16) * 64 + kr * 32 + quad * 8);
        aqB[kr] = *(const bf16x8*)(qh + base + (size_t)(qbaseB + l16) * 64 + kr * 32 + quad * 8);
    }

    bf16x8 ones;
#pragma unroll
    for (int j = 0; j < 8; j++) ones[j] = (short)0x3F80;

    f32x4 oA[4] = {}, oB[4] = {};
    f32x4 laccA = {}, laccB = {};
    u16* pw = sP + wave * 16 * 72;

    auto STAGE = [&](int kb, int b) {
        const int krow0 = kb * 64;
#pragma unroll
        for (int i = 0; i < 2; i++) {
            int u = (i * 4 + wave) * 64 + lane;
            int row = u >> 3, cu = (u & 7) ^ (row & 7);
            gld16(kh + base + (size_t)(krow0 + row) * 64 + cu * 8, &sK[b][0] + u * 8);
        }
#pragma unroll
        for (int i = 0; i < 2; i++) {
            int u = (i * 4 + wave) * 64 + lane;
            int row = u >> 3, cu = (u & 7) ^ (row & 7);
            gld16(vhT + ((size_t)(bh * 64 + row)) * 1024 + krow0 + cu * 8, &sVT[b][0] + u * 8);
        }
    };

    STAGE(0, 0);
    __syncthreads();

    const int last = 15 - pr;
    int cur = 0;
    for (int kb = 0; kb <= last; kb++) {
        if (kb < last) STAGE(kb + 1, cur ^ 1);         // prefetch overlaps compute
        const int krow0 = kb * 64;
        const bool actA = (kb <= pr);
        const u16* sKc = sK[cur];
        const u16* sVc = sVT[cur];

        bf16x8 bk[4][2];
#pragma unroll
        for (int kc = 0; kc < 4; kc++) {
            int row = kc * 16 + l16;
#pragma unroll
            for (int kr = 0; kr < 2; kr++)
                bk[kc][kr] = *(const bf16x8*)(sKc + row * 64 + (((kr * 4 + quad) ^ (row & 7)) * 8));
        }
        f32x4 scA[4], scB[4];
        __builtin_amdgcn_s_setprio(1);
#pragma unroll
        for (int kc = 0; kc < 4; kc++) {
            f32x4 z = {};
            z = MFMA16(aqB[0], bk[kc][0], z, 0, 0, 0);
            z = MFMA16(aqB[1], bk[kc][1], z, 0, 0, 0);
            scB[kc] = z;
        }
        if (actA) {
#pragma unroll
            for (int kc = 0; kc < 4; kc++) {
                f32x4 z = {};
                z = MFMA16(aqA[0], bk[kc][0], z, 0, 0, 0);
                z = MFMA16(aqA[1], bk[kc][1], z, 0, 0, 0);
                scA[kc] = z;
            }
        }
        __builtin_amdgcn_s_setprio(0);

        // ---- softmax A (only while its causal range lasts), then B; sP reused ----
        bf16x8 apA0, apA1, apB0, apB1;
        if (actA) {
            const bool dmA = (krow0 + 63 > qbaseA);
#pragma unroll
            for (int kc = 0; kc < 4; kc++)
#pragma unroll
                for (int r = 0; r < 4; r++) {
                    float xv = fminf(scA[kc][r] * e2, 43.f);
                    float pv = exp2f(xv);
                    if (dmA) {
                        int kcol = krow0 + kc * 16 + l16;
                        int qrow = qbaseA + quad * 4 + r;
                        if (kcol > qrow) pv = 0.f;
                    }
                    pw[(quad * 4 + r) * 72 + kc * 16 + l16] = f2bf(pv);
                }
            apA0 = *(const bf16x8*)(pw + l16 * 72 + quad * 8);
            apA1 = *(const bf16x8*)(pw + l16 * 72 + 32 + quad * 8);
        }
        {
            const bool dmB = (krow0 + 63 > qbaseB);
#pragma unroll
            for (int kc = 0; kc < 4; kc++)
#pragma unroll
                for (int r = 0; r < 4; r++) {
                    float xv = fminf(scB[kc][r] * e2, 43.f);
                    float pv = exp2f(xv);
                    if (dmB) {
                        int kcol = krow0 + kc * 16 + l16;
                        int qrow = qbaseB + quad * 4 + r;
                        if (kcol > qrow) pv = 0.f;
                    }
                    pw[(quad * 4 + r) * 72 + kc * 16 + l16] = f2bf(pv);
                }
            apB0 = *(const bf16x8*)(pw + l16 * 72 + quad * 8);
            apB1 = *(const bf16x8*)(pw + l16 * 72 + 32 + quad * 8);
        }

        bf16x8 bv[4][2];
#pragma unroll
        for (int nt = 0; nt < 4; nt++) {
            int row = nt * 16 + l16;
#pragma unroll
            for (int kr = 0; kr < 2; kr++)
                bv[nt][kr] = *(const bf16x8*)(sVc + row * 64 + (((kr * 4 + quad) ^ (row & 7)) * 8));
        }
        __builtin_amdgcn_s_setprio(1);
#pragma unroll
        for (int nt = 0; nt < 4; nt++) {
            oB[nt] = MFMA16(apB0, bv[nt][0], oB[nt], 0, 0, 0);
            oB[nt] = MFMA16(apB1, bv[nt][1], oB[nt], 0, 0, 0);
        }
        laccB = MFMA16(apB0, ones, laccB, 0, 0, 0);
        laccB = MFMA16(apB1, ones, laccB, 0, 0, 0);
        if (actA) {
#pragma unroll
            for (int nt = 0; nt < 4; nt++) {
                oA[nt] = MFMA16(apA0, bv[nt][0], oA[nt], 0, 0, 0);
                oA[nt] = MFMA16(apA1, bv[nt][1], oA[nt], 0, 0, 0);
            }
            laccA = MFMA16(apA0, ones, laccA, 0, 0, 0);
            laccA = MFMA16(apA1, ones, laccA, 0, 0, 0);
        }
        __builtin_amdgcn_s_setprio(0);
        __syncthreads();
        cur ^= 1;
    }

    const int b = bh >> 4, h = bh & 15;
#pragma unroll
    for (int nt = 0; nt < 4; nt++)
#pragma unroll
        for (int r = 0; r < 4; r++) {
            int d = nt * 16 + l16;
            int qrA = qbaseA + quad * 4 + r;
            int qrB = qbaseB + quad * 4 + r;
            y[(size_t)(b * 1024 + qrA) * 1024 + h * 64 + d] = f2bf(oA[nt][r] / laccA[r]);
            y[(size_t)(b * 1024 + qrB) * 1024 + h * 64 + d] = f2bf(oB[nt][r] / laccB[r]);
        }
}

extern "C" void kernel_launch(void* const* d_in, const int* in_sizes, int n_in,
                              void* d_out, int out_size, void* d_ws, size_t ws_size,
                              hipStream_t stream)
{
    const float* key   = (const float*)d_in[0];
    const float* value = (const float*)d_in[1];
    const float* query = (const float*)d_in[2];
    const float* Wk = (const float*)d_in[3];
    const float* bk = (const float*)d_in[4];
    const float* Wq = (const float*)d_in[5];
    const float* bq = (const float*)d_in[6];
    const float* Wv = (const float*)d_in[7];
    const float* bv = (const float*)d_in[8];
    const float* Wp = (const float*)d_in[9];
    const float* bp = (const float*)d_in[10];

    char* ws = (char*)d_ws;
    u16* xq  = (u16*)(ws + (size_t)( 0 << 20));
    u16* xk  = (u16*)(ws + (size_t)( 8 << 20));
    u16* xv  = (u16*)(ws + (size_t)(16 << 20));
    u16* wqb = (u16*)(ws + (size_t)(24 << 20));
    u16* wkb = (u16*)(ws + (size_t)(26 << 20));
    u16* wvb = (u16*)(ws + (size_t)(28 << 20));
    u16* wpb = (u16*)(ws + (size_t)(30 << 20));
    u16* qh  = (u16*)(ws + (size_t)(32 << 20));
    u16* kh  = (u16*)(ws + (size_t)(40 << 20));
    u16* vhT = (u16*)(ws + (size_t)(48 << 20));
    u16* y   = xq;   // xq dead after QKV GEMM

    CvtArgs ca;
    ca.src[0] = query; ca.dst[0] = xq;
    ca.src[1] = key;   ca.dst[1] = xk;
    ca.src[2] = value; ca.dst[2] = xv;
    ca.src[3] = Wq;    ca.dst[3] = wqb;
    ca.src[4] = Wk;    ca.dst[4] = wkb;
    ca.src[5] = Wv;    ca.dst[5] = wvb;
    ca.src[6] = Wp;    ca.dst[6] = wpb;
    hipLaunchKernelGGL(cvt_kernel, dim3(8192), dim3(256), 0, stream, ca);

    Gemm3Args g3;
    g3.g[0] = GemmArgs{xq, wqb, bq, (void*)qh,  0};
    g3.g[1] = GemmArgs{xk, wkb, bk, (void*)kh,  0};
    g3.g[2] = GemmArgs{xv, wvb, bv, (void*)vhT, 2};
    hipLaunchKernelGGL(gemm_qkv, dim3(256, 1, 3), dim3(256), 0, stream, g3);

    hipLaunchKernelGGL(attn_kernel, dim3(512), dim3(256), 0, stream, qh, kh, vhT, y);

    hipLaunchKernelGGL(gemm_p, dim3(256), dim3(256), 0, stream, y, wpb, bp, (float*)d_out);
}